// Round 3
// baseline (344.420 us; speedup 1.0000x reference)
//
#include <hip/hip_runtime.h>
#include <math.h>

// GRU cell, per-position weights. B=16,N=207,C=64,H=64 -> 3312 positions.
// v3: latency-capacity attack. No Wch LDS staging (4.3 KB LDS -> 30 waves/CU),
// wave-uniform gate mapping (rp=t&3, jg=t>>2), forced 8 waves/EU, unroll-4
// float4 stream = 8 loads in flight/wave. Wch read cold in phase 2, coalesced.

#define GC 64
#define GH 64
#define J3 192
#define WPP (GC * J3)

__global__ __launch_bounds__(192, 8) void gru_cell_v3(
    const float* __restrict__ x,      // (P, 64)
    const float* __restrict__ state,  // (P, 64)
    const float* __restrict__ Wx,     // (P, 64, 192)
    const float* __restrict__ Wh,     // (P, 64, 192)
    const float* __restrict__ b,      // (P, 192)
    float* __restrict__ out)          // (P, 64)
{
    const int pos = blockIdx.x;
    const int t = threadIdx.x;        // 0..191
    const int rp = t & 3;             // row phase: rows rp, rp+4, ..., rp+60
    const int jg = t >> 2;            // column group: columns 4*jg .. 4*jg+3

    __shared__ float x_s[GC];
    __shared__ float h_s[GH];
    __shared__ float part[4][J3 + 4];
    __shared__ float rh_s[GH];
    __shared__ float z_s[GH];

    if (t < GC)           x_s[t]      = x[(size_t)pos * GC + t];
    else if (t < GC + GH) h_s[t - GC] = state[(size_t)pos * GH + (t - GC)];

    const float bv = b[(size_t)pos * J3 + t];   // hoisted, overlaps barrier
    __syncthreads();

    const float4* __restrict__ Wx4 = (const float4*)(Wx + (size_t)pos * WPP);
    const float4* __restrict__ Wh4 = (const float4*)(Wh + (size_t)pos * WPP);

    float4 acc = {0.f, 0.f, 0.f, 0.f};
    const bool gate = (t < 2 * GH);   // wave-uniform: waves 0,1 = r,z columns

    if (gate) {
        #pragma unroll 4
        for (int i = 0; i < 16; ++i) {
            const int c = 4 * i + rp;
            float4 wx4 = Wx4[(size_t)c * 48 + jg];
            float4 wh4 = Wh4[(size_t)c * 48 + jg];
            const float xs = x_s[c];
            const float hs = h_s[c];
            acc.x += xs * wx4.x + hs * wh4.x;
            acc.y += xs * wx4.y + hs * wh4.y;
            acc.z += xs * wx4.z + hs * wh4.z;
            acc.w += xs * wx4.w + hs * wh4.w;
        }
    } else {
        #pragma unroll 8
        for (int i = 0; i < 16; ++i) {
            const int c = 4 * i + rp;
            float4 wx4 = Wx4[(size_t)c * 48 + jg];
            const float xs = x_s[c];
            acc.x += xs * wx4.x; acc.y += xs * wx4.y;
            acc.z += xs * wx4.z; acc.w += xs * wx4.w;
        }
    }

    *((float4*)&part[rp][4 * jg]) = acc;
    __syncthreads();

    // Thread t owns column t.
    float v = part[0][t] + part[1][t] + part[2][t] + part[3][t] + bv;
    if (t < GH) {
        float r = 1.f / (1.f + expf(-v));
        rh_s[t] = r * h_s[t];
    } else if (t < 2 * GH) {
        z_s[t - GH] = 1.f / (1.f + expf(-v));
    }
    __syncthreads();

    if (t >= 2 * GH) {
        const int jc = t - 2 * GH;
        // (r*h) . Wch, Wch read directly from global: for fixed c, lanes span
        // columns 128..191 -> coalesced 256 B per instruction.
        const float* __restrict__ Wch = Wh + (size_t)pos * WPP + 2 * GH + jc;
        float s = 0.f;
        #pragma unroll 8
        for (int c = 0; c < GC; ++c) s += rh_s[c] * Wch[(size_t)c * J3];
        const float hc = tanhf(v + s);
        const float z = z_s[jc];
        out[(size_t)pos * GH + jc] = (1.f - z) * h_s[jc] + z * hc;
    }
}

extern "C" void kernel_launch(void* const* d_in, const int* in_sizes, int n_in,
                              void* d_out, int out_size, void* d_ws, size_t ws_size,
                              hipStream_t stream) {
    const float* x     = (const float*)d_in[0];
    const float* state = (const float*)d_in[1];
    const float* Wx    = (const float*)d_in[2];
    const float* Wh    = (const float*)d_in[3];
    const float* b     = (const float*)d_in[4];
    float* out = (float*)d_out;

    const int npos = in_sizes[0] / GC;   // 3312

    gru_cell_v3<<<npos, 192, 0, stream>>>(x, state, Wx, Wh, b, out);
}

// Round 5
// 340.233 us; speedup vs baseline: 1.0123x; 1.0123x over previous
//
#include <hip/hip_runtime.h>
#include <math.h>

// GRU cell, per-position weights. B=16,N=207,C=64,H=64 -> 3312 positions.
// v5: one wave per position, NO LDS, NO barriers. All cross-lane data moves
// via __shfl (register-level, race-free; v4's single-wave LDS+barrier pattern
// was state-dependent after graph replay). Lane j owns output columns
// {j, 64+j, 128+j}. Weights read exactly once, coalesced 256 B/instr, loads
// explicitly batched 4 rows x 5 streams with outer unroll 2 (~40 loads per
// window); __launch_bounds__(64,4) gives a 128-VGPR budget so they stay in
// flight.

#define GC 64
#define GH 64
#define J3 192
#define WPP (GC * J3)   // 12288

__global__ __launch_bounds__(64, 4) void gru_cell_v5(
    const float* __restrict__ x,      // (P, 64)
    const float* __restrict__ state,  // (P, 64)
    const float* __restrict__ Wx,     // (P, 64, 192)
    const float* __restrict__ Wh,     // (P, 64, 192)
    const float* __restrict__ b,      // (P, 192)
    float* __restrict__ out)          // (P, 64)
{
    const int pos = blockIdx.x;
    const int j = threadIdx.x;        // 0..63

    const float xj = x[(size_t)pos * GC + j];      // lane j holds x[j]
    const float hj = state[(size_t)pos * GH + j];  // lane j holds h[j]

    const float* __restrict__ Wxp = Wx + (size_t)pos * WPP + j;
    const float* __restrict__ Whp = Wh + (size_t)pos * WPP + j;

    float axr = 0.f, axz = 0.f, axc = 0.f, ahr = 0.f, ahz = 0.f;

    // Main GEMV over 64 rows. Per 4-row batch: 20 independent scalar loads
    // issued before any FMA; broadcasts of x[c], h[c] via __shfl (no memory).
    #pragma unroll 2
    for (int c0 = 0; c0 < GC; c0 += 4) {
        float wxr[4], wxz[4], wxc[4], whr[4], whz[4];
        #pragma unroll
        for (int u = 0; u < 4; ++u) {
            const float* px = Wxp + (size_t)(c0 + u) * J3;
            wxr[u] = px[0];
            wxz[u] = px[64];
            wxc[u] = px[128];
            const float* ph = Whp + (size_t)(c0 + u) * J3;
            whr[u] = ph[0];
            whz[u] = ph[64];
        }
        #pragma unroll
        for (int u = 0; u < 4; ++u) {
            const float xs = __shfl(xj, c0 + u, 64);
            const float hs = __shfl(hj, c0 + u, 64);
            axr += xs * wxr[u];
            axz += xs * wxz[u];
            axc += xs * wxc[u];
            ahr += hs * whr[u];
            ahz += hs * whz[u];
        }
    }

    const float* __restrict__ bp = b + (size_t)pos * J3 + j;
    const float br = bp[0], bz = bp[64], bc = bp[128];

    const float r = 1.f / (1.f + expf(-(axr + ahr + br)));
    const float z = 1.f / (1.f + expf(-(axz + ahz + bz)));
    const float rh = r * hj;               // lane j holds (r*h)[j]

    // Candidate GEMV: s_j = sum_c (r*h)[c] * Wch[c][j]; Wch = Wh cols 128..191,
    // read here for the first and only time. rh broadcast via __shfl.
    const float* __restrict__ Wch = Wh + (size_t)pos * WPP + 2 * GH + j;
    float s = 0.f;
    #pragma unroll 2
    for (int c0 = 0; c0 < GC; c0 += 8) {
        float w[8];
        #pragma unroll
        for (int u = 0; u < 8; ++u) w[u] = Wch[(size_t)(c0 + u) * J3];
        #pragma unroll
        for (int u = 0; u < 8; ++u) s += __shfl(rh, c0 + u, 64) * w[u];
    }

    const float hc = tanhf(axc + s + bc);
    out[(size_t)pos * GH + j] = (1.f - z) * hj + z * hc;
}

extern "C" void kernel_launch(void* const* d_in, const int* in_sizes, int n_in,
                              void* d_out, int out_size, void* d_ws, size_t ws_size,
                              hipStream_t stream) {
    const float* x     = (const float*)d_in[0];
    const float* state = (const float*)d_in[1];
    const float* Wx    = (const float*)d_in[2];
    const float* Wh    = (const float*)d_in[3];
    const float* b     = (const float*)d_in[4];
    float* out = (float*)d_out;

    const int npos = in_sizes[0] / GC;   // 3312

    gru_cell_v5<<<npos, 64, 0, stream>>>(x, state, Wx, Wh, b, out);
}